// Round 7
// baseline (878.633 us; speedup 1.0000x reference)
//
#include <hip/hip_runtime.h>
#include <stdint.h>

typedef __attribute__((ext_vector_type(8))) short v8s;
typedef __attribute__((ext_vector_type(4))) short v4s;
typedef __attribute__((ext_vector_type(4))) float v4f;

#define MFMA(a, b, c) __builtin_amdgcn_mfma_f32_16x16x32_bf16((a), (b), (c), 0, 0, 0)

__device__ __forceinline__ unsigned short f2bf(float f) {
    unsigned int u = __float_as_uint(f);
    u += 0x7fffu + ((u >> 16) & 1u);           // RNE, inputs are finite
    return (unsigned short)(u >> 16);
}
__device__ __forceinline__ float bf2f(unsigned short h) {
    return __uint_as_float(((unsigned int)h) << 16);
}

// async global->LDS, 16B per lane. LDS dest = wave-uniform base (+ lane*16 by HW).
__device__ __forceinline__ void gload16(const void* g, void* l) {
    __builtin_amdgcn_global_load_lds((const __attribute__((address_space(1))) void*)g,
                                     (__attribute__((address_space(3))) void*)l, 16, 0, 0);
}

// ---- paired-line swizzle for [R][32]bf16 arrays, 64B logical rows (validated R6) ----
// line = row>>1 (128B), slot(row,c) = (((row&1)<<2)|c) ^ (line&7); byte = line*128 + slot*16.
__device__ __forceinline__ int pl_addr(int row, int c) {
    return ((row >> 1) << 7) + ((((((row & 1) << 2) | c)) ^ ((row >> 1) & 7)) << 4);
}

#define NB 4
#define SEQ 4096
#define ED 1024

// ---- workspace byte offsets (peak 224 MB < proven-good 232 MB) ----
#define XHI_OFF   (0ll)
#define XLO_OFF   (33554432ll)
#define XT_OFF    (67108864ll)
#define YHI_OFF   (100663296ll)
#define YLO_OFF   (134217728ll)
#define SBUF_OFF  (167772160ll)    // 64 MB: 160M..224M
#define WQH_OFF   (222298112ll)    // scratch inside SBUF tail (dead before gemm_s)
#define WQL_OFF   (224395264ll)
#define WKH_OFF   (226492416ll)
#define WKL_OFF   (228589568ll)
#define MTH_OFF   (230686720ll)
#define MTL_OFF   (232783872ll)
#define WS_NEED   (234881024ll)    // 224 MB

// ============ prep_x: split X -> bf16 hi/lo, and transpose -> XT[b][d][s] ============
__global__ __launch_bounds__(256) void prep_x(const float* __restrict__ x,
                                              unsigned short* __restrict__ xhi,
                                              unsigned short* __restrict__ xlo,
                                              unsigned short* __restrict__ xt) {
    __shared__ float tile[64][65];
    int b = blockIdx.z, s0 = blockIdx.x * 64, d0 = blockIdx.y * 64;
    int t = threadIdx.x;
#pragma unroll
    for (int i = 0; i < 16; ++i) {
        int idx = t + i * 256;
        int r = idx >> 6, c = idx & 63;
        long gi = (long)(b * SEQ + s0 + r) * ED + d0 + c;
        float v = x[gi];
        tile[r][c] = v;
        unsigned short hi = f2bf(v);
        xhi[gi] = hi;
        xlo[gi] = f2bf(v - bf2f(hi));
    }
    __syncthreads();
#pragma unroll
    for (int i = 0; i < 16; ++i) {
        int idx = t + i * 256;
        int r = idx >> 6, c = idx & 63;   // r: local d, c: local s
        xt[(long)(b * ED + d0 + r) * SEQ + s0 + c] = f2bf(tile[c][r]);
    }
}

// ============ prep_w2: split Wq, Wk (row-major, no transpose) into bf16 hi/lo ============
__global__ __launch_bounds__(256) void prep_w2(const float* __restrict__ wq,
                                               const float* __restrict__ wk,
                                               unsigned short* __restrict__ wqh,
                                               unsigned short* __restrict__ wql,
                                               unsigned short* __restrict__ wkh,
                                               unsigned short* __restrict__ wkl) {
    const float* w = blockIdx.z ? wk : wq;
    unsigned short* oh = blockIdx.z ? wkh : wqh;
    unsigned short* ol = blockIdx.z ? wkl : wql;
    long idx = ((long)blockIdx.x * 256 + threadIdx.x) * 4;
    v4f v = *(const v4f*)(w + idx);
    v4s ph, pl;
#pragma unroll
    for (int e = 0; e < 4; ++e) {
        unsigned short hi = f2bf(v[e]);
        ph[e] = (short)hi;
        pl[e] = (short)f2bf(v[e] - bf2f(hi));
    }
    *(v4s*)(oh + idx) = ph;
    *(v4s*)(ol + idx) = pl;
}

// ============ gemm_m: MT[e'][e] = sum_f Wk[e'][f] * Wq[e][f]  (4-pass split, R5 loop) ====
__global__ __launch_bounds__(256, 2) void gemm_m(const unsigned short* __restrict__ ah,
                                                 const unsigned short* __restrict__ al,
                                                 const unsigned short* __restrict__ bh,
                                                 const unsigned short* __restrict__ bl,
                                                 unsigned short* __restrict__ ch,
                                                 unsigned short* __restrict__ cl) {
    __shared__ __align__(16) unsigned char lds[65536];
    int m0 = blockIdx.x * 128, n0 = blockIdx.y * 128;
    int tid = threadIdx.x, lane = tid & 63, wave = tid >> 6;
    int mo = (wave & 1) * 64, no = (wave >> 1) * 64;
    int lr = lane >> 3;
    int scol = (((lane & 7) ^ lr) << 4);
    v4f vzero = {0.f, 0.f, 0.f, 0.f};
    v4f acc[4][4];
#pragma unroll
    for (int i = 0; i < 4; ++i)
#pragma unroll
        for (int j = 0; j < 4; ++j) acc[i][j] = vzero;
    int cb0 = 16 * (lane >> 4);

    for (int ks = 0; ks < 16; ++ks) {
        __syncthreads();
#pragma unroll
        for (int j = 0; j < 4; ++j) {
            int c = j * 4 + wave;
            int row = c * 8 + lr;
            long ga = ((long)(m0 + row) * ED + ks * 64) * 2 + scol;
            long gb = ((long)(n0 + row) * ED + ks * 64) * 2 + scol;
            unsigned loff = c * 1024;
            gload16((const unsigned char*)ah + ga, lds + loff);
            gload16((const unsigned char*)al + ga, lds + 16384 + loff);
            gload16((const unsigned char*)bh + gb, lds + 32768 + loff);
            gload16((const unsigned char*)bl + gb, lds + 49152 + loff);
        }
        __syncthreads();
#pragma unroll
        for (int kk = 0; kk < 2; ++kk) {
            v8s fah[4], fal[4], fbh[4], fbl[4];
#pragma unroll
            for (int i = 0; i < 4; ++i) {
                int ra = mo + i * 16 + (lane & 15);
                int ca = (kk * 64 + cb0) ^ ((ra & 7) << 4);
                fah[i] = *(const v8s*)(lds +         ra * 128 + ca);
                fal[i] = *(const v8s*)(lds + 16384 + ra * 128 + ca);
                int rb = no + i * 16 + (lane & 15);
                int cbb = (kk * 64 + cb0) ^ ((rb & 7) << 4);
                fbh[i] = *(const v8s*)(lds + 32768 + rb * 128 + cbb);
                fbl[i] = *(const v8s*)(lds + 49152 + rb * 128 + cbb);
            }
#pragma unroll
            for (int i = 0; i < 4; ++i)
#pragma unroll
                for (int j = 0; j < 4; ++j) {
                    acc[i][j] = MFMA(fah[i], fbh[j], acc[i][j]);
                    acc[i][j] = MFMA(fah[i], fbl[j], acc[i][j]);
                    acc[i][j] = MFMA(fal[i], fbh[j], acc[i][j]);
                    acc[i][j] = MFMA(fal[i], fbl[j], acc[i][j]);
                }
        }
    }
#pragma unroll
    for (int i = 0; i < 4; ++i)
#pragma unroll
        for (int j = 0; j < 4; ++j)
#pragma unroll
            for (int r = 0; r < 4; ++r) {
                int row = m0 + mo + i * 16 + (lane >> 4) * 4 + r;
                int col = n0 + no + j * 16 + (lane & 15);
                float v = acc[i][j][r];
                unsigned short hi = f2bf(v);
                long o = (long)row * ED + col;
                ch[o] = hi;
                cl[o] = f2bf(v - bf2f(hi));
            }
}

// ============ split-GEMM v2: BM=128 BN=256 BK=32, 3-slot LDS, counted vmcnt ============
// 512 threads, 8 waves (2M x 4N), per-wave 64x64 output, 3 mfma passes (hh, hl, lh).
// Slot (48KB): Ah[128][32]@0 | Al@8K | Bh[256][32]@16K | Bl@32K. 3 slots = 144KB.
// Stage tile t+2 while computing t; one raw barrier per tile; vmcnt(6) counted wait.
template <int EMIT_SPLIT>
__device__ __forceinline__ void split_gemm_v2(const unsigned char* ah, const unsigned char* al,
                                              const unsigned char* bh, const unsigned char* bl,
                                              long arow0, long brow0,
                                              unsigned short* ch, unsigned short* cl,
                                              float* sbuf, float sscale,
                                              unsigned char* lds) {
    int m0 = blockIdx.x * 128, n0 = blockIdx.y * 256;
    int tid = threadIdx.x, lane = tid & 63, wid = tid >> 6;
    int mo = (wid >> 2) * 64, no = (wid & 3) * 64;
    v4f vzero = {0.f, 0.f, 0.f, 0.f};
    v4f acc[4][4];
#pragma unroll
    for (int i = 0; i < 4; ++i)
#pragma unroll
        for (int j = 0; j < 4; ++j) acc[i][j] = vzero;

    // stage-side lane terms (paired-line inversion, validated R6)
    int t2 = (lane & 7) ^ (lane >> 3);
    int rsub = 2 * (lane >> 3) + (t2 >> 2);
    int gcb = (t2 & 3) << 4;
    int cfr = lane >> 4;

    // this wave's 6 stage chunks: A chunk wid (16 rows), B chunks wid and wid+8
    long gA  = (arow0 + m0 + 16 * wid + rsub) * 2048 + gcb;
    long gB0 = (brow0 + n0 + 16 * wid + rsub) * 2048 + gcb;
    long gB1 = (brow0 + n0 + 16 * (wid + 8) + rsub) * 2048 + gcb;
    unsigned lA  = wid * 1024u;
    unsigned lB0 = 16384u + wid * 1024u;
    unsigned lB1 = 16384u + (wid + 8) * 1024u;

#define STG(ks, s)                                                   \
    {                                                                \
        long ko = (long)(ks) * 64;                                   \
        unsigned Ls = (s) * 49152u;                                  \
        gload16(ah + gA + ko,  lds + Ls + lA);                       \
        gload16(al + gA + ko,  lds + Ls + 8192 + lA);                \
        gload16(bh + gB0 + ko, lds + Ls + lB0);                      \
        gload16(bh + gB1 + ko, lds + Ls + lB1);                      \
        gload16(bl + gB0 + ko, lds + Ls + 16384 + lB0);              \
        gload16(bl + gB1 + ko, lds + Ls + 16384 + lB1);              \
    }

    STG(0, 0);
    STG(1, 1);
    for (int t = 0; t < 32; ++t) {
        // counted wait: own outstanding beyond 6 are tile-t slices -> retired.
        // barrier: all waves' tile-t slices landed. Un-landed loads target slot (t+2)%3.
        if (t == 31) { asm volatile("s_waitcnt vmcnt(0)" ::: "memory"); }
        else         { asm volatile("s_waitcnt vmcnt(6)" ::: "memory"); }
        __builtin_amdgcn_s_barrier();
        __builtin_amdgcn_sched_barrier(0);
        if (t + 2 < 32) STG(t + 2, (t + 2) % 3);
        unsigned Lc = (unsigned)(t % 3) * 49152u;
        v8s fbh[4], fbl[4];
#pragma unroll
        for (int j = 0; j < 4; ++j) {
            int rb = no + j * 16 + (lane & 15);
            int pb = pl_addr(rb, cfr);
            fbh[j] = *(const v8s*)(lds + Lc + 16384 + pb);
            fbl[j] = *(const v8s*)(lds + Lc + 32768 + pb);
        }
#pragma unroll
        for (int i = 0; i < 4; ++i) {
            int ra = mo + i * 16 + (lane & 15);
            int pa = pl_addr(ra, cfr);
            v8s fah = *(const v8s*)(lds + Lc + pa);
            v8s fal = *(const v8s*)(lds + Lc + 8192 + pa);
#pragma unroll
            for (int j = 0; j < 4; ++j) {
                acc[i][j] = MFMA(fah, fbh[j], acc[i][j]);
                acc[i][j] = MFMA(fah, fbl[j], acc[i][j]);
                acc[i][j] = MFMA(fal, fbh[j], acc[i][j]);
            }
        }
    }
#undef STG

#pragma unroll
    for (int i = 0; i < 4; ++i)
#pragma unroll
        for (int j = 0; j < 4; ++j)
#pragma unroll
            for (int r = 0; r < 4; ++r) {
                int row = m0 + mo + i * 16 + (lane >> 4) * 4 + r;
                int col = n0 + no + j * 16 + (lane & 15);
                float v = acc[i][j][r];
                if (EMIT_SPLIT) {
                    unsigned short hi = f2bf(v);
                    long o = (arow0 + row) * (long)ED + col;
                    ch[o] = hi;
                    cl[o] = f2bf(v - bf2f(hi));
                } else {
                    sbuf[(long)row * SEQ + col] = v * sscale;
                }
            }
}

// ============ gemm_y: Y = X x M (split out), v2 pipeline ============
__global__ __launch_bounds__(512, 2) void gemm_y(const unsigned short* __restrict__ ah,
                                                 const unsigned short* __restrict__ al,
                                                 const unsigned short* __restrict__ bh,
                                                 const unsigned short* __restrict__ bl,
                                                 unsigned short* __restrict__ ch,
                                                 unsigned short* __restrict__ cl) {
    __shared__ __align__(16) unsigned char lds[147456];
    split_gemm_v2<1>((const unsigned char*)ah, (const unsigned char*)al,
                     (const unsigned char*)bh, (const unsigned char*)bl,
                     0, 0, ch, cl, nullptr, 1.0f, lds);
}

// ============ gemm_s: S = (Y X^T)/32 for one batch (fp32 out), v2 pipeline ============
__global__ __launch_bounds__(512, 2) void gemm_s(const unsigned short* __restrict__ qhi,
                                                 const unsigned short* __restrict__ qlo,
                                                 const unsigned short* __restrict__ khi,
                                                 const unsigned short* __restrict__ klo,
                                                 float* __restrict__ sbuf, int b) {
    __shared__ __align__(16) unsigned char lds[147456];
    split_gemm_v2<0>((const unsigned char*)qhi, (const unsigned char*)qlo,
                     (const unsigned char*)khi, (const unsigned char*)klo,
                     (long)b * SEQ, (long)b * SEQ, nullptr, nullptr, sbuf, 0.03125f, lds);
}

// ============ softmax_rows: P = exp(S-m)/l, bf16, packed in-place (first 8KB of row) ============
__global__ __launch_bounds__(256) void softmax_rows(float* __restrict__ sbuf) {
    int row = blockIdx.x * 4 + (threadIdx.x >> 6);
    int lane = threadIdx.x & 63;
    float* base = sbuf + (long)row * SEQ;
    v4f v[16];
    float m = -INFINITY;
#pragma unroll
    for (int j = 0; j < 16; ++j) {
        v[j] = *(const v4f*)(base + j * 256 + lane * 4);
#pragma unroll
        for (int e = 0; e < 4; ++e) m = fmaxf(m, v[j][e]);
    }
#pragma unroll
    for (int o = 1; o < 64; o <<= 1) m = fmaxf(m, __shfl_xor(m, o));
    float s = 0.f;
#pragma unroll
    for (int j = 0; j < 16; ++j)
#pragma unroll
        for (int e = 0; e < 4; ++e) {
            float p = __expf(v[j][e] - m);
            s += p;
            v[j][e] = p;
        }
#pragma unroll
    for (int o = 1; o < 64; o <<= 1) s += __shfl_xor(s, o);
    float inv = 1.0f / s;
    unsigned short* ob = (unsigned short*)base;
#pragma unroll
    for (int j = 0; j < 16; ++j) {
        v4s pk;
#pragma unroll
        for (int e = 0; e < 4; ++e) pk[e] = (short)f2bf(v[j][e] * inv);
        *(v4s*)(ob + j * 256 + lane * 4) = pk;
    }
}

// ============ gemm_pv: O[q][d] = P X (R5-proven version, 32KB single-buffer) ============
__global__ __launch_bounds__(256, 4) void gemm_pv(const float* __restrict__ sbuf,
                                                  const unsigned short* __restrict__ xt,
                                                  float* __restrict__ out, int b) {
    __shared__ __align__(16) unsigned char lds[32768];
    int m0 = blockIdx.x * 128, n0 = blockIdx.y * 128;
    int tid = threadIdx.x, lane = tid & 63, wave = tid >> 6;
    int mo = (wave & 1) * 64, no = (wave >> 1) * 64;
    const unsigned char* pbytes = (const unsigned char*)sbuf;
    int lr = lane >> 3;
    int scol = (((lane & 7) ^ lr) << 4);
    v4f vzero = {0.f, 0.f, 0.f, 0.f};
    v4f acc[4][4];
#pragma unroll
    for (int i = 0; i < 4; ++i)
#pragma unroll
        for (int j = 0; j < 4; ++j) acc[i][j] = vzero;
    int cb0 = 16 * (lane >> 4);

    for (int ks = 0; ks < 64; ++ks) {
        __syncthreads();
#pragma unroll
        for (int j = 0; j < 4; ++j) {
            int c = j * 4 + wave;
            int row = c * 8 + lr;
            long ga = (long)(m0 + row) * 16384 + ks * 128 + scol;
            long gb = ((long)(b * ED + n0 + row) * SEQ + ks * 64) * 2 + scol;
            unsigned loff = c * 1024;
            gload16(pbytes + ga, lds + loff);
            gload16((const unsigned char*)xt + gb, lds + 16384 + loff);
        }
        __syncthreads();
#pragma unroll
        for (int kk = 0; kk < 2; ++kk) {
            v8s fa[4], fb[4];
#pragma unroll
            for (int i = 0; i < 4; ++i) {
                int ra = mo + i * 16 + (lane & 15);
                int ca = (kk * 64 + cb0) ^ ((ra & 7) << 4);
                fa[i] = *(const v8s*)(lds +         ra * 128 + ca);
                int rb = no + i * 16 + (lane & 15);
                int cbb = (kk * 64 + cb0) ^ ((rb & 7) << 4);
                fb[i] = *(const v8s*)(lds + 16384 + rb * 128 + cbb);
            }
#pragma unroll
            for (int i = 0; i < 4; ++i)
#pragma unroll
                for (int j = 0; j < 4; ++j)
                    acc[i][j] = MFMA(fa[i], fb[j], acc[i][j]);
        }
    }
#pragma unroll
    for (int i = 0; i < 4; ++i)
#pragma unroll
        for (int j = 0; j < 4; ++j)
#pragma unroll
            for (int r = 0; r < 4; ++r) {
                int row = m0 + mo + i * 16 + (lane >> 4) * 4 + r;
                int col = n0 + no + j * 16 + (lane & 15);
                out[(long)(b * SEQ + row) * ED + col] = acc[i][j][r];
            }
}

extern "C" void kernel_launch(void* const* d_in, const int* in_sizes, int n_in,
                              void* d_out, int out_size, void* d_ws, size_t ws_size,
                              hipStream_t stream) {
    const float* x  = (const float*)d_in[0];
    const float* wq = (const float*)d_in[1];
    const float* wk = (const float*)d_in[2];
    unsigned char* ws = (unsigned char*)d_ws;
    unsigned short* xhi = (unsigned short*)(ws + XHI_OFF);
    unsigned short* xlo = (unsigned short*)(ws + XLO_OFF);
    unsigned short* xt  = (unsigned short*)(ws + XT_OFF);
    unsigned short* yhi = (unsigned short*)(ws + YHI_OFF);
    unsigned short* ylo = (unsigned short*)(ws + YLO_OFF);
    float*          sbuf= (float*)(ws + SBUF_OFF);
    unsigned short* wqh = (unsigned short*)(ws + WQH_OFF);
    unsigned short* wql = (unsigned short*)(ws + WQL_OFF);
    unsigned short* wkh = (unsigned short*)(ws + WKH_OFF);
    unsigned short* wkl = (unsigned short*)(ws + WKL_OFF);
    unsigned short* mth = (unsigned short*)(ws + MTH_OFF);
    unsigned short* mtl = (unsigned short*)(ws + MTL_OFF);

    prep_x<<<dim3(64, 16, 4), 256, 0, stream>>>(x, xhi, xlo, xt);
    prep_w2<<<dim3(1024, 1, 2), 256, 0, stream>>>(wq, wk, wqh, wql, wkh, wkl);
    gemm_m<<<dim3(8, 8), 256, 0, stream>>>(wkh, wkl, wqh, wql, mth, mtl);
    gemm_y<<<dim3(128, 4), 512, 0, stream>>>(xhi, xlo, mth, mtl, yhi, ylo);
    for (int b = 0; b < NB; ++b) {
        gemm_s<<<dim3(32, 16), 512, 0, stream>>>(yhi, ylo, xhi, xlo, sbuf, b);
        softmax_rows<<<1024, 256, 0, stream>>>(sbuf);
        gemm_pv<<<dim3(32, 8), 256, 0, stream>>>(sbuf, xt, (float*)d_out, b);
    }
}

// Round 8
// 709.066 us; speedup vs baseline: 1.2391x; 1.2391x over previous
//
#include <hip/hip_runtime.h>
#include <stdint.h>

typedef __attribute__((ext_vector_type(8))) short v8s;
typedef __attribute__((ext_vector_type(4))) short v4s;
typedef __attribute__((ext_vector_type(4))) float v4f;

#define MFMA(a, b, c) __builtin_amdgcn_mfma_f32_16x16x32_bf16((a), (b), (c), 0, 0, 0)

__device__ __forceinline__ unsigned short f2bf(float f) {
    unsigned int u = __float_as_uint(f);
    u += 0x7fffu + ((u >> 16) & 1u);           // RNE, inputs are finite
    return (unsigned short)(u >> 16);
}
__device__ __forceinline__ float bf2f(unsigned short h) {
    return __uint_as_float(((unsigned int)h) << 16);
}

// async global->LDS, 16B per lane. LDS dest = wave-uniform base (+ lane*16 by HW).
__device__ __forceinline__ void gload16(const void* g, void* l) {
    __builtin_amdgcn_global_load_lds((const __attribute__((address_space(1))) void*)g,
                                     (__attribute__((address_space(3))) void*)l, 16, 0, 0);
}

#define NB 4
#define SEQ 4096
#define ED 1024

// ---- workspace byte offsets (peak 224 MB < proven-good 232 MB) ----
#define XHI_OFF   (0ll)
#define XLO_OFF   (33554432ll)
#define XT_OFF    (67108864ll)
#define YHI_OFF   (100663296ll)
#define YLO_OFF   (134217728ll)
#define SBUF_OFF  (167772160ll)    // 64 MB: 160M..224M
#define WQH_OFF   (222298112ll)    // scratch inside SBUF tail (dead before gemm_s)
#define WQL_OFF   (224395264ll)
#define WKH_OFF   (226492416ll)
#define WKL_OFF   (228589568ll)
#define MTH_OFF   (230686720ll)
#define MTL_OFF   (232783872ll)
#define WS_NEED   (234881024ll)    // 224 MB

// ============ prep_x: split X -> bf16 hi/lo, and transpose -> XT[b][d][s] ============
__global__ __launch_bounds__(256) void prep_x(const float* __restrict__ x,
                                              unsigned short* __restrict__ xhi,
                                              unsigned short* __restrict__ xlo,
                                              unsigned short* __restrict__ xt) {
    __shared__ float tile[64][65];
    int b = blockIdx.z, s0 = blockIdx.x * 64, d0 = blockIdx.y * 64;
    int t = threadIdx.x;
#pragma unroll
    for (int i = 0; i < 16; ++i) {
        int idx = t + i * 256;
        int r = idx >> 6, c = idx & 63;
        long gi = (long)(b * SEQ + s0 + r) * ED + d0 + c;
        float v = x[gi];
        tile[r][c] = v;
        unsigned short hi = f2bf(v);
        xhi[gi] = hi;
        xlo[gi] = f2bf(v - bf2f(hi));
    }
    __syncthreads();
#pragma unroll
    for (int i = 0; i < 16; ++i) {
        int idx = t + i * 256;
        int r = idx >> 6, c = idx & 63;   // r: local d, c: local s
        xt[(long)(b * ED + d0 + r) * SEQ + s0 + c] = f2bf(tile[c][r]);
    }
}

// ============ prep_w2: split Wq, Wk (row-major, no transpose) into bf16 hi/lo ============
__global__ __launch_bounds__(256) void prep_w2(const float* __restrict__ wq,
                                               const float* __restrict__ wk,
                                               unsigned short* __restrict__ wqh,
                                               unsigned short* __restrict__ wql,
                                               unsigned short* __restrict__ wkh,
                                               unsigned short* __restrict__ wkl) {
    const float* w = blockIdx.z ? wk : wq;
    unsigned short* oh = blockIdx.z ? wkh : wqh;
    unsigned short* ol = blockIdx.z ? wkl : wql;
    long idx = ((long)blockIdx.x * 256 + threadIdx.x) * 4;
    v4f v = *(const v4f*)(w + idx);
    v4s ph, pl;
#pragma unroll
    for (int e = 0; e < 4; ++e) {
        unsigned short hi = f2bf(v[e]);
        ph[e] = (short)hi;
        pl[e] = (short)f2bf(v[e] - bf2f(hi));
    }
    *(v4s*)(oh + idx) = ph;
    *(v4s*)(ol + idx) = pl;
}

// ============ gemm_m: MT[e'][e] = sum_f Wk[e'][f] * Wq[e][f]  (4-pass split) ============
__global__ __launch_bounds__(256, 2) void gemm_m(const unsigned short* __restrict__ ah,
                                                 const unsigned short* __restrict__ al,
                                                 const unsigned short* __restrict__ bh,
                                                 const unsigned short* __restrict__ bl,
                                                 unsigned short* __restrict__ ch,
                                                 unsigned short* __restrict__ cl) {
    __shared__ __align__(16) unsigned char lds[65536];
    int m0 = blockIdx.x * 128, n0 = blockIdx.y * 128;
    int tid = threadIdx.x, lane = tid & 63, wave = tid >> 6;
    int mo = (wave & 1) * 64, no = (wave >> 1) * 64;
    int lr = lane >> 3;
    int scol = (((lane & 7) ^ lr) << 4);
    v4f vzero = {0.f, 0.f, 0.f, 0.f};
    v4f acc[4][4];
#pragma unroll
    for (int i = 0; i < 4; ++i)
#pragma unroll
        for (int j = 0; j < 4; ++j) acc[i][j] = vzero;
    int cb0 = 16 * (lane >> 4);

    for (int ks = 0; ks < 16; ++ks) {
        __syncthreads();
#pragma unroll
        for (int j = 0; j < 4; ++j) {
            int c = j * 4 + wave;
            int row = c * 8 + lr;
            long ga = ((long)(m0 + row) * ED + ks * 64) * 2 + scol;
            long gb = ((long)(n0 + row) * ED + ks * 64) * 2 + scol;
            unsigned loff = c * 1024;
            gload16((const unsigned char*)ah + ga, lds + loff);
            gload16((const unsigned char*)al + ga, lds + 16384 + loff);
            gload16((const unsigned char*)bh + gb, lds + 32768 + loff);
            gload16((const unsigned char*)bl + gb, lds + 49152 + loff);
        }
        __syncthreads();
#pragma unroll
        for (int kk = 0; kk < 2; ++kk) {
            v8s fah[4], fal[4], fbh[4], fbl[4];
#pragma unroll
            for (int i = 0; i < 4; ++i) {
                int ra = mo + i * 16 + (lane & 15);
                int ca = (kk * 64 + cb0) ^ ((ra & 7) << 4);
                fah[i] = *(const v8s*)(lds +         ra * 128 + ca);
                fal[i] = *(const v8s*)(lds + 16384 + ra * 128 + ca);
                int rb = no + i * 16 + (lane & 15);
                int cbb = (kk * 64 + cb0) ^ ((rb & 7) << 4);
                fbh[i] = *(const v8s*)(lds + 32768 + rb * 128 + cbb);
                fbl[i] = *(const v8s*)(lds + 49152 + rb * 128 + cbb);
            }
#pragma unroll
            for (int i = 0; i < 4; ++i)
#pragma unroll
                for (int j = 0; j < 4; ++j) {
                    acc[i][j] = MFMA(fah[i], fbh[j], acc[i][j]);
                    acc[i][j] = MFMA(fah[i], fbl[j], acc[i][j]);
                    acc[i][j] = MFMA(fal[i], fbh[j], acc[i][j]);
                    acc[i][j] = MFMA(fal[i], fbl[j], acc[i][j]);
                }
        }
    }
#pragma unroll
    for (int i = 0; i < 4; ++i)
#pragma unroll
        for (int j = 0; j < 4; ++j)
#pragma unroll
            for (int r = 0; r < 4; ++r) {
                int row = m0 + mo + i * 16 + (lane >> 4) * 4 + r;
                int col = n0 + no + j * 16 + (lane & 15);
                float v = acc[i][j][r];
                unsigned short hi = f2bf(v);
                long o = (long)row * ED + col;
                ch[o] = hi;
                cl[o] = f2bf(v - bf2f(hi));
            }
}

// ============ gemm_y: Y[16384,1024] = X x M  (A=x hi/lo, B^T=M^T hi/lo, 3 passes) ============
__global__ __launch_bounds__(256, 2) void gemm_y(const unsigned short* __restrict__ ah,
                                                 const unsigned short* __restrict__ al,
                                                 const unsigned short* __restrict__ bh,
                                                 const unsigned short* __restrict__ bl,
                                                 unsigned short* __restrict__ ch,
                                                 unsigned short* __restrict__ cl) {
    __shared__ __align__(16) unsigned char lds[65536];
    int m0 = blockIdx.x * 128, n0 = blockIdx.y * 128;
    int tid = threadIdx.x, lane = tid & 63, wave = tid >> 6;
    int mo = (wave & 1) * 64, no = (wave >> 1) * 64;
    int lr = lane >> 3;
    int scol = (((lane & 7) ^ lr) << 4);
    v4f vzero = {0.f, 0.f, 0.f, 0.f};
    v4f acc[4][4];
#pragma unroll
    for (int i = 0; i < 4; ++i)
#pragma unroll
        for (int j = 0; j < 4; ++j) acc[i][j] = vzero;
    int cb0 = 16 * (lane >> 4);

    for (int ks = 0; ks < 16; ++ks) {
        __syncthreads();
#pragma unroll
        for (int j = 0; j < 4; ++j) {
            int c = j * 4 + wave;
            int row = c * 8 + lr;
            long ga = ((long)(m0 + row) * ED + ks * 64) * 2 + scol;
            long gb = ((long)(n0 + row) * ED + ks * 64) * 2 + scol;
            unsigned loff = c * 1024;
            gload16((const unsigned char*)ah + ga, lds + loff);
            gload16((const unsigned char*)al + ga, lds + 16384 + loff);
            gload16((const unsigned char*)bh + gb, lds + 32768 + loff);
            gload16((const unsigned char*)bl + gb, lds + 49152 + loff);
        }
        __syncthreads();
#pragma unroll
        for (int kk = 0; kk < 2; ++kk) {
            v8s fah[4], fal[4], fbh[4], fbl[4];
#pragma unroll
            for (int i = 0; i < 4; ++i) {
                int ra = mo + i * 16 + (lane & 15);
                int ca = (kk * 64 + cb0) ^ ((ra & 7) << 4);
                fah[i] = *(const v8s*)(lds +         ra * 128 + ca);
                fal[i] = *(const v8s*)(lds + 16384 + ra * 128 + ca);
                int rb = no + i * 16 + (lane & 15);
                int cbb = (kk * 64 + cb0) ^ ((rb & 7) << 4);
                fbh[i] = *(const v8s*)(lds + 32768 + rb * 128 + cbb);
                fbl[i] = *(const v8s*)(lds + 49152 + rb * 128 + cbb);
            }
#pragma unroll
            for (int i = 0; i < 4; ++i)
#pragma unroll
                for (int j = 0; j < 4; ++j) {
                    acc[i][j] = MFMA(fah[i], fbh[j], acc[i][j]);
                    acc[i][j] = MFMA(fah[i], fbl[j], acc[i][j]);
                    acc[i][j] = MFMA(fal[i], fbh[j], acc[i][j]);
                }
        }
    }
#pragma unroll
    for (int i = 0; i < 4; ++i)
#pragma unroll
        for (int j = 0; j < 4; ++j)
#pragma unroll
            for (int r = 0; r < 4; ++r) {
                int row = m0 + mo + i * 16 + (lane >> 4) * 4 + r;
                int col = n0 + no + j * 16 + (lane & 15);
                float v = acc[i][j][r];
                unsigned short hi = f2bf(v);
                long o = (long)row * ED + col;
                ch[o] = hi;
                cl[o] = f2bf(v - bf2f(hi));
            }
}

// ============ gemm_s1: S~[q][t] = (Yh Xh^T)/32, ONE bf16 pass (errors fixed in softmax_fix) ====
__global__ __launch_bounds__(256, 4) void gemm_s1(const unsigned short* __restrict__ qh,
                                                  const unsigned short* __restrict__ kh,
                                                  float* __restrict__ sbuf, int b) {
    __shared__ __align__(16) unsigned char lds[32768];   // Ah | Bh, 16KB each
    int m0 = blockIdx.x * 128, n0 = blockIdx.y * 128;
    int tid = threadIdx.x, lane = tid & 63, wave = tid >> 6;
    int mo = (wave & 1) * 64, no = (wave >> 1) * 64;
    int lr = lane >> 3;
    int scol = (((lane & 7) ^ lr) << 4);
    v4f vzero = {0.f, 0.f, 0.f, 0.f};
    v4f acc[4][4];
#pragma unroll
    for (int i = 0; i < 4; ++i)
#pragma unroll
        for (int j = 0; j < 4; ++j) acc[i][j] = vzero;
    int cb0 = 16 * (lane >> 4);

    for (int ks = 0; ks < 16; ++ks) {
        __syncthreads();
#pragma unroll
        for (int j = 0; j < 4; ++j) {
            int c = j * 4 + wave;
            int row = c * 8 + lr;
            long ga = ((long)(b * SEQ + m0 + row) * ED + ks * 64) * 2 + scol;
            long gb = ((long)(b * SEQ + n0 + row) * ED + ks * 64) * 2 + scol;
            unsigned loff = c * 1024;
            gload16((const unsigned char*)qh + ga, lds + loff);
            gload16((const unsigned char*)kh + gb, lds + 16384 + loff);
        }
        __syncthreads();
#pragma unroll
        for (int kk = 0; kk < 2; ++kk) {
            v8s fa[4], fb[4];
#pragma unroll
            for (int i = 0; i < 4; ++i) {
                int ra = mo + i * 16 + (lane & 15);
                int ca = (kk * 64 + cb0) ^ ((ra & 7) << 4);
                fa[i] = *(const v8s*)(lds +         ra * 128 + ca);
                int rb = no + i * 16 + (lane & 15);
                int cbb = (kk * 64 + cb0) ^ ((rb & 7) << 4);
                fb[i] = *(const v8s*)(lds + 16384 + rb * 128 + cbb);
            }
#pragma unroll
            for (int i = 0; i < 4; ++i)
#pragma unroll
                for (int j = 0; j < 4; ++j)
                    acc[i][j] = MFMA(fa[i], fb[j], acc[i][j]);
        }
    }
#pragma unroll
    for (int i = 0; i < 4; ++i)
#pragma unroll
        for (int j = 0; j < 4; ++j)
#pragma unroll
            for (int r = 0; r < 4; ++r) {
                int row = m0 + mo + i * 16 + (lane >> 4) * 4 + r;
                int col = n0 + no + j * 16 + (lane & 15);
                sbuf[(long)row * SEQ + col] = acc[i][j][r] * 0.03125f;
            }
}

// ============ softmax_fix: approx-S row softmax with exact fixup of near-max entries ============
// 1 wave per row, 2 rows per 128-thread block. Window W=60 below observed max: entries there
// get an exact fp32 recompute from (yhi+ylo)·(xhi+xlo); everything else has p < e^-21.
__global__ __launch_bounds__(128) void softmax_fix(float* __restrict__ sbuf,
                                                   const unsigned short* __restrict__ yhi,
                                                   const unsigned short* __restrict__ ylo,
                                                   const unsigned short* __restrict__ xhi,
                                                   const unsigned short* __restrict__ xlo,
                                                   int b) {
    __shared__ float rowbuf[2][4096];
    __shared__ int cnt[2];
    __shared__ int list[2][64];
    int w = threadIdx.x >> 6, lane = threadIdx.x & 63;
    int row = blockIdx.x * 2 + w;
    float* base = sbuf + (long)row * SEQ;
    if (lane == 0) cnt[w] = 0;

    // phase 1: load row -> LDS, observed max
    float mhat = -INFINITY;
#pragma unroll
    for (int j = 0; j < 16; ++j) {
        v4f v = *(const v4f*)(base + j * 256 + lane * 4);
        *(v4f*)(&rowbuf[w][j * 256 + lane * 4]) = v;
#pragma unroll
        for (int e = 0; e < 4; ++e) mhat = fmaxf(mhat, v[e]);
    }
#pragma unroll
    for (int o = 1; o < 64; o <<= 1) mhat = fmaxf(mhat, __shfl_xor(mhat, o));

    // phase 2: candidate detection
    float T = mhat - 60.0f;
#pragma unroll
    for (int j = 0; j < 16; ++j) {
        v4f v = *(const v4f*)(&rowbuf[w][j * 256 + lane * 4]);
#pragma unroll
        for (int e = 0; e < 4; ++e)
            if (v[e] > T) {
                int idx = atomicAdd(&cnt[w], 1);
                if (idx < 64) list[w][idx] = j * 256 + lane * 4 + e;
            }
    }
    __syncthreads();

    // phase 3: exact recompute of candidates (wave-cooperative fp32 dot over K=1024)
    int n = cnt[w] < 64 ? cnt[w] : 64;
    long ybase = ((long)b * SEQ + row) * ED;
    float mcorr = -INFINITY;
    for (int c = 0; c < n; ++c) {
        int col = list[w][c];
        long xbase = ((long)b * SEQ + col) * ED;
        int k0 = lane * 16;
        v8s yh0 = *(const v8s*)(yhi + ybase + k0), yh1 = *(const v8s*)(yhi + ybase + k0 + 8);
        v8s yl0 = *(const v8s*)(ylo + ybase + k0), yl1 = *(const v8s*)(ylo + ybase + k0 + 8);
        v8s xh0 = *(const v8s*)(xhi + xbase + k0), xh1 = *(const v8s*)(xhi + xbase + k0 + 8);
        v8s xl0 = *(const v8s*)(xlo + xbase + k0), xl1 = *(const v8s*)(xlo + xbase + k0 + 8);
        float s = 0.f;
#pragma unroll
        for (int e = 0; e < 8; ++e) {
            float y0 = bf2f((unsigned short)yh0[e]) + bf2f((unsigned short)yl0[e]);
            float x0 = bf2f((unsigned short)xh0[e]) + bf2f((unsigned short)xl0[e]);
            s += y0 * x0;
            float y1 = bf2f((unsigned short)yh1[e]) + bf2f((unsigned short)yl1[e]);
            float x1 = bf2f((unsigned short)xh1[e]) + bf2f((unsigned short)xl1[e]);
            s += y1 * x1;
        }
#pragma unroll
        for (int o = 1; o < 64; o <<= 1) s += __shfl_xor(s, o);
        s *= 0.03125f;
        if (lane == 0) rowbuf[w][col] = s;
        mcorr = fmaxf(mcorr, s);
    }
    __syncthreads();

    // phase 4: softmax over corrected row, write P bf16 packed in-place
    float M = mcorr;   // true max is always a candidate
    float sum = 0.f;
    v4f pv[16];
#pragma unroll
    for (int j = 0; j < 16; ++j) {
        v4f sv = *(const v4f*)(&rowbuf[w][j * 256 + lane * 4]);
#pragma unroll
        for (int e = 0; e < 4; ++e) {
            float p = __expf(sv[e] - M);
            sum += p;
            pv[j][e] = p;
        }
    }
#pragma unroll
    for (int o = 1; o < 64; o <<= 1) sum += __shfl_xor(sum, o);
    float inv = 1.0f / sum;
    unsigned short* ob = (unsigned short*)base;
#pragma unroll
    for (int j = 0; j < 16; ++j) {
        v4s pk;
#pragma unroll
        for (int e = 0; e < 4; ++e) pk[e] = (short)f2bf(pv[j][e] * inv);
        *(v4s*)(ob + j * 256 + lane * 4) = pk;
    }
}

// ============ gemm_pv: O[q][d] = P X for one batch. A = P (16KB row slots), B^T = XT ============
__global__ __launch_bounds__(256, 4) void gemm_pv(const float* __restrict__ sbuf,
                                                  const unsigned short* __restrict__ xt,
                                                  float* __restrict__ out, int b) {
    __shared__ __align__(16) unsigned char lds[32768];
    int m0 = blockIdx.x * 128, n0 = blockIdx.y * 128;
    int tid = threadIdx.x, lane = tid & 63, wave = tid >> 6;
    int mo = (wave & 1) * 64, no = (wave >> 1) * 64;
    const unsigned char* pbytes = (const unsigned char*)sbuf;
    int lr = lane >> 3;
    int scol = (((lane & 7) ^ lr) << 4);
    v4f vzero = {0.f, 0.f, 0.f, 0.f};
    v4f acc[4][4];
#pragma unroll
    for (int i = 0; i < 4; ++i)
#pragma unroll
        for (int j = 0; j < 4; ++j) acc[i][j] = vzero;
    int cb0 = 16 * (lane >> 4);

    for (int ks = 0; ks < 64; ++ks) {
        __syncthreads();
#pragma unroll
        for (int j = 0; j < 4; ++j) {
            int c = j * 4 + wave;
            int row = c * 8 + lr;
            long ga = (long)(m0 + row) * 16384 + ks * 128 + scol;
            long gb = ((long)(b * ED + n0 + row) * SEQ + ks * 64) * 2 + scol;
            unsigned loff = c * 1024;
            gload16(pbytes + ga, lds + loff);
            gload16((const unsigned char*)xt + gb, lds + 16384 + loff);
        }
        __syncthreads();
#pragma unroll
        for (int kk = 0; kk < 2; ++kk) {
            v8s fa[4], fb[4];
#pragma unroll
            for (int i = 0; i < 4; ++i) {
                int ra = mo + i * 16 + (lane & 15);
                int ca = (kk * 64 + cb0) ^ ((ra & 7) << 4);
                fa[i] = *(const v8s*)(lds +         ra * 128 + ca);
                int rb = no + i * 16 + (lane & 15);
                int cbb = (kk * 64 + cb0) ^ ((rb & 7) << 4);
                fb[i] = *(const v8s*)(lds + 16384 + rb * 128 + cbb);
            }
#pragma unroll
            for (int i = 0; i < 4; ++i)
#pragma unroll
                for (int j = 0; j < 4; ++j)
                    acc[i][j] = MFMA(fa[i], fb[j], acc[i][j]);
        }
    }
#pragma unroll
    for (int i = 0; i < 4; ++i)
#pragma unroll
        for (int j = 0; j < 4; ++j)
#pragma unroll
            for (int r = 0; r < 4; ++r) {
                int row = m0 + mo + i * 16 + (lane >> 4) * 4 + r;
                int col = n0 + no + j * 16 + (lane & 15);
                out[(long)(b * SEQ + row) * ED + col] = acc[i][j][r];
            }
}

extern "C" void kernel_launch(void* const* d_in, const int* in_sizes, int n_in,
                              void* d_out, int out_size, void* d_ws, size_t ws_size,
                              hipStream_t stream) {
    const float* x  = (const float*)d_in[0];
    const float* wq = (const float*)d_in[1];
    const float* wk = (const float*)d_in[2];
    unsigned char* ws = (unsigned char*)d_ws;
    unsigned short* xhi = (unsigned short*)(ws + XHI_OFF);
    unsigned short* xlo = (unsigned short*)(ws + XLO_OFF);
    unsigned short* xt  = (unsigned short*)(ws + XT_OFF);
    unsigned short* yhi = (unsigned short*)(ws + YHI_OFF);
    unsigned short* ylo = (unsigned short*)(ws + YLO_OFF);
    float*          sbuf= (float*)(ws + SBUF_OFF);
    unsigned short* wqh = (unsigned short*)(ws + WQH_OFF);
    unsigned short* wql = (unsigned short*)(ws + WQL_OFF);
    unsigned short* wkh = (unsigned short*)(ws + WKH_OFF);
    unsigned short* wkl = (unsigned short*)(ws + WKL_OFF);
    unsigned short* mth = (unsigned short*)(ws + MTH_OFF);
    unsigned short* mtl = (unsigned short*)(ws + MTL_OFF);

    prep_x<<<dim3(64, 16, 4), 256, 0, stream>>>(x, xhi, xlo, xt);
    prep_w2<<<dim3(1024, 1, 2), 256, 0, stream>>>(wq, wk, wqh, wql, wkh, wkl);
    gemm_m<<<dim3(8, 8), 256, 0, stream>>>(wkh, wkl, wqh, wql, mth, mtl);
    gemm_y<<<dim3(128, 8), 256, 0, stream>>>(xhi, xlo, mth, mtl, yhi, ylo);
    for (int b = 0; b < NB; ++b) {
        gemm_s1<<<dim3(32, 32), 256, 0, stream>>>(yhi, xhi, sbuf, b);
        softmax_fix<<<2048, 128, 0, stream>>>(sbuf, yhi, ylo, xhi, xlo, b);
        gemm_pv<<<dim3(32, 8), 256, 0, stream>>>(sbuf, xt, (float*)d_out, b);
    }
}

// Round 9
// 359.943 us; speedup vs baseline: 2.4410x; 1.9699x over previous
//
#include <hip/hip_runtime.h>
#include <stdint.h>

typedef __attribute__((ext_vector_type(8))) short v8s;
typedef __attribute__((ext_vector_type(4))) short v4s;
typedef __attribute__((ext_vector_type(4))) float v4f;

#define MFMA(a, b, c) __builtin_amdgcn_mfma_f32_16x16x32_bf16((a), (b), (c), 0, 0, 0)

__device__ __forceinline__ unsigned short f2bf(float f) {
    unsigned int u = __float_as_uint(f);
    u += 0x7fffu + ((u >> 16) & 1u);           // RNE, inputs are finite
    return (unsigned short)(u >> 16);
}
__device__ __forceinline__ float bf2f(unsigned short h) {
    return __uint_as_float(((unsigned int)h) << 16);
}
__device__ __forceinline__ float h2f(unsigned short u) {
    _Float16 h;
    __builtin_memcpy(&h, &u, 2);
    return (float)h;
}
__device__ __forceinline__ unsigned short f2h(float f) {
    _Float16 h = (_Float16)f;
    unsigned short u;
    __builtin_memcpy(&u, &h, 2);
    return u;
}

// async global->LDS, 16B per lane. LDS dest = wave-uniform base (+ lane*16 by HW).
__device__ __forceinline__ void gload16(const void* g, void* l) {
    __builtin_amdgcn_global_load_lds((const __attribute__((address_space(1))) void*)g,
                                     (__attribute__((address_space(3))) void*)l, 16, 0, 0);
}

#define NB 4
#define SEQ 4096
#define ED 1024

// ---- workspace byte offsets (peak 172 MB < proven-good 224 MB) ----
#define XHI_OFF   (0ll)
#define XLO_OFF   (33554432ll)
#define YHI_OFF   (67108864ll)
#define YLO_OFF   (100663296ll)
#define SBUF_OFF  (134217728ll)    // 32 MB fp16 S~ per batch
#define WQH_OFF   (167772160ll)
#define WQL_OFF   (169869312ll)
#define WKH_OFF   (171966464ll)
#define WKL_OFF   (174063616ll)
#define MTH_OFF   (176160768ll)
#define MTL_OFF   (178257920ll)
#define WS_NEED   (180355072ll)    // 172 MB

// ============ prep_x: split X -> bf16 hi/lo (pure elementwise, no transpose) ============
__global__ __launch_bounds__(256) void prep_x(const float* __restrict__ x,
                                              unsigned short* __restrict__ xhi,
                                              unsigned short* __restrict__ xlo) {
    long idx = ((long)blockIdx.x * 256 + threadIdx.x) * 4;
    v4f v = *(const v4f*)(x + idx);
    v4s ph, pl;
#pragma unroll
    for (int e = 0; e < 4; ++e) {
        unsigned short hi = f2bf(v[e]);
        ph[e] = (short)hi;
        pl[e] = (short)f2bf(v[e] - bf2f(hi));
    }
    *(v4s*)(xhi + idx) = ph;
    *(v4s*)(xlo + idx) = pl;
}

// ============ prep_w2: split Wq, Wk (row-major) into bf16 hi/lo ============
__global__ __launch_bounds__(256) void prep_w2(const float* __restrict__ wq,
                                               const float* __restrict__ wk,
                                               unsigned short* __restrict__ wqh,
                                               unsigned short* __restrict__ wql,
                                               unsigned short* __restrict__ wkh,
                                               unsigned short* __restrict__ wkl) {
    const float* w = blockIdx.z ? wk : wq;
    unsigned short* oh = blockIdx.z ? wkh : wqh;
    unsigned short* ol = blockIdx.z ? wkl : wql;
    long idx = ((long)blockIdx.x * 256 + threadIdx.x) * 4;
    v4f v = *(const v4f*)(w + idx);
    v4s ph, pl;
#pragma unroll
    for (int e = 0; e < 4; ++e) {
        unsigned short hi = f2bf(v[e]);
        ph[e] = (short)hi;
        pl[e] = (short)f2bf(v[e] - bf2f(hi));
    }
    *(v4s*)(oh + idx) = ph;
    *(v4s*)(ol + idx) = pl;
}

// ============ gemm_m: MT[e'][e] = sum_f Wk[e'][f] * Wq[e][f]  (4-pass split) ============
__global__ __launch_bounds__(256, 2) void gemm_m(const unsigned short* __restrict__ ah,
                                                 const unsigned short* __restrict__ al,
                                                 const unsigned short* __restrict__ bh,
                                                 const unsigned short* __restrict__ bl,
                                                 unsigned short* __restrict__ ch,
                                                 unsigned short* __restrict__ cl) {
    __shared__ __align__(16) unsigned char lds[65536];
    int m0 = blockIdx.x * 128, n0 = blockIdx.y * 128;
    int tid = threadIdx.x, lane = tid & 63, wave = tid >> 6;
    int mo = (wave & 1) * 64, no = (wave >> 1) * 64;
    int lr = lane >> 3;
    int scol = (((lane & 7) ^ lr) << 4);
    v4f vzero = {0.f, 0.f, 0.f, 0.f};
    v4f acc[4][4];
#pragma unroll
    for (int i = 0; i < 4; ++i)
#pragma unroll
        for (int j = 0; j < 4; ++j) acc[i][j] = vzero;
    int cb0 = 16 * (lane >> 4);

    for (int ks = 0; ks < 16; ++ks) {
        __syncthreads();
#pragma unroll
        for (int j = 0; j < 4; ++j) {
            int c = j * 4 + wave;
            int row = c * 8 + lr;
            long ga = ((long)(m0 + row) * ED + ks * 64) * 2 + scol;
            long gb = ((long)(n0 + row) * ED + ks * 64) * 2 + scol;
            unsigned loff = c * 1024;
            gload16((const unsigned char*)ah + ga, lds + loff);
            gload16((const unsigned char*)al + ga, lds + 16384 + loff);
            gload16((const unsigned char*)bh + gb, lds + 32768 + loff);
            gload16((const unsigned char*)bl + gb, lds + 49152 + loff);
        }
        __syncthreads();
#pragma unroll
        for (int kk = 0; kk < 2; ++kk) {
            v8s fah[4], fal[4], fbh[4], fbl[4];
#pragma unroll
            for (int i = 0; i < 4; ++i) {
                int ra = mo + i * 16 + (lane & 15);
                int ca = (kk * 64 + cb0) ^ ((ra & 7) << 4);
                fah[i] = *(const v8s*)(lds +         ra * 128 + ca);
                fal[i] = *(const v8s*)(lds + 16384 + ra * 128 + ca);
                int rb = no + i * 16 + (lane & 15);
                int cbb = (kk * 64 + cb0) ^ ((rb & 7) << 4);
                fbh[i] = *(const v8s*)(lds + 32768 + rb * 128 + cbb);
                fbl[i] = *(const v8s*)(lds + 49152 + rb * 128 + cbb);
            }
#pragma unroll
            for (int i = 0; i < 4; ++i)
#pragma unroll
                for (int j = 0; j < 4; ++j) {
                    acc[i][j] = MFMA(fah[i], fbh[j], acc[i][j]);
                    acc[i][j] = MFMA(fah[i], fbl[j], acc[i][j]);
                    acc[i][j] = MFMA(fal[i], fbh[j], acc[i][j]);
                    acc[i][j] = MFMA(fal[i], fbl[j], acc[i][j]);
                }
        }
    }
#pragma unroll
    for (int i = 0; i < 4; ++i)
#pragma unroll
        for (int j = 0; j < 4; ++j)
#pragma unroll
            for (int r = 0; r < 4; ++r) {
                int row = m0 + mo + i * 16 + (lane >> 4) * 4 + r;
                int col = n0 + no + j * 16 + (lane & 15);
                float v = acc[i][j][r];
                unsigned short hi = f2bf(v);
                long o = (long)row * ED + col;
                ch[o] = hi;
                cl[o] = f2bf(v - bf2f(hi));
            }
}

// ============ gemm_y: Y[16384,1024] = X x M  (A=x hi/lo, B^T=M^T hi/lo, 3 passes) ============
__global__ __launch_bounds__(256, 2) void gemm_y(const unsigned short* __restrict__ ah,
                                                 const unsigned short* __restrict__ al,
                                                 const unsigned short* __restrict__ bh,
                                                 const unsigned short* __restrict__ bl,
                                                 unsigned short* __restrict__ ch,
                                                 unsigned short* __restrict__ cl) {
    __shared__ __align__(16) unsigned char lds[65536];
    int m0 = blockIdx.x * 128, n0 = blockIdx.y * 128;
    int tid = threadIdx.x, lane = tid & 63, wave = tid >> 6;
    int mo = (wave & 1) * 64, no = (wave >> 1) * 64;
    int lr = lane >> 3;
    int scol = (((lane & 7) ^ lr) << 4);
    v4f vzero = {0.f, 0.f, 0.f, 0.f};
    v4f acc[4][4];
#pragma unroll
    for (int i = 0; i < 4; ++i)
#pragma unroll
        for (int j = 0; j < 4; ++j) acc[i][j] = vzero;
    int cb0 = 16 * (lane >> 4);

    for (int ks = 0; ks < 16; ++ks) {
        __syncthreads();
#pragma unroll
        for (int j = 0; j < 4; ++j) {
            int c = j * 4 + wave;
            int row = c * 8 + lr;
            long ga = ((long)(m0 + row) * ED + ks * 64) * 2 + scol;
            long gb = ((long)(n0 + row) * ED + ks * 64) * 2 + scol;
            unsigned loff = c * 1024;
            gload16((const unsigned char*)ah + ga, lds + loff);
            gload16((const unsigned char*)al + ga, lds + 16384 + loff);
            gload16((const unsigned char*)bh + gb, lds + 32768 + loff);
            gload16((const unsigned char*)bl + gb, lds + 49152 + loff);
        }
        __syncthreads();
#pragma unroll
        for (int kk = 0; kk < 2; ++kk) {
            v8s fah[4], fal[4], fbh[4], fbl[4];
#pragma unroll
            for (int i = 0; i < 4; ++i) {
                int ra = mo + i * 16 + (lane & 15);
                int ca = (kk * 64 + cb0) ^ ((ra & 7) << 4);
                fah[i] = *(const v8s*)(lds +         ra * 128 + ca);
                fal[i] = *(const v8s*)(lds + 16384 + ra * 128 + ca);
                int rb = no + i * 16 + (lane & 15);
                int cbb = (kk * 64 + cb0) ^ ((rb & 7) << 4);
                fbh[i] = *(const v8s*)(lds + 32768 + rb * 128 + cbb);
                fbl[i] = *(const v8s*)(lds + 49152 + rb * 128 + cbb);
            }
#pragma unroll
            for (int i = 0; i < 4; ++i)
#pragma unroll
                for (int j = 0; j < 4; ++j) {
                    acc[i][j] = MFMA(fah[i], fbh[j], acc[i][j]);
                    acc[i][j] = MFMA(fah[i], fbl[j], acc[i][j]);
                    acc[i][j] = MFMA(fal[i], fbh[j], acc[i][j]);
                }
        }
    }
#pragma unroll
    for (int i = 0; i < 4; ++i)
#pragma unroll
        for (int j = 0; j < 4; ++j)
#pragma unroll
            for (int r = 0; r < 4; ++r) {
                int row = m0 + mo + i * 16 + (lane >> 4) * 4 + r;
                int col = n0 + no + j * 16 + (lane & 15);
                float v = acc[i][j][r];
                unsigned short hi = f2bf(v);
                long o = (long)row * ED + col;
                ch[o] = hi;
                cl[o] = f2bf(v - bf2f(hi));
            }
}

// ============ gemm_s1: S~[q][t] = (Yh Xh^T)/32, ONE bf16 pass, fp16 output ============
__global__ __launch_bounds__(256, 4) void gemm_s1(const unsigned short* __restrict__ qh,
                                                  const unsigned short* __restrict__ kh,
                                                  unsigned short* __restrict__ sbuf, int b) {
    __shared__ __align__(16) unsigned char lds[32768];   // Ah | Bh, 16KB each
    int m0 = blockIdx.x * 128, n0 = blockIdx.y * 128;
    int tid = threadIdx.x, lane = tid & 63, wave = tid >> 6;
    int mo = (wave & 1) * 64, no = (wave >> 1) * 64;
    int lr = lane >> 3;
    int scol = (((lane & 7) ^ lr) << 4);
    v4f vzero = {0.f, 0.f, 0.f, 0.f};
    v4f acc[4][4];
#pragma unroll
    for (int i = 0; i < 4; ++i)
#pragma unroll
        for (int j = 0; j < 4; ++j) acc[i][j] = vzero;
    int cb0 = 16 * (lane >> 4);

    for (int ks = 0; ks < 16; ++ks) {
        __syncthreads();
#pragma unroll
        for (int j = 0; j < 4; ++j) {
            int c = j * 4 + wave;
            int row = c * 8 + lr;
            long ga = ((long)(b * SEQ + m0 + row) * ED + ks * 64) * 2 + scol;
            long gb = ((long)(b * SEQ + n0 + row) * ED + ks * 64) * 2 + scol;
            unsigned loff = c * 1024;
            gload16((const unsigned char*)qh + ga, lds + loff);
            gload16((const unsigned char*)kh + gb, lds + 16384 + loff);
        }
        __syncthreads();
#pragma unroll
        for (int kk = 0; kk < 2; ++kk) {
            v8s fa[4], fb[4];
#pragma unroll
            for (int i = 0; i < 4; ++i) {
                int ra = mo + i * 16 + (lane & 15);
                int ca = (kk * 64 + cb0) ^ ((ra & 7) << 4);
                fa[i] = *(const v8s*)(lds +         ra * 128 + ca);
                int rb = no + i * 16 + (lane & 15);
                int cbb = (kk * 64 + cb0) ^ ((rb & 7) << 4);
                fb[i] = *(const v8s*)(lds + 16384 + rb * 128 + cbb);
            }
#pragma unroll
            for (int i = 0; i < 4; ++i)
#pragma unroll
                for (int j = 0; j < 4; ++j)
                    acc[i][j] = MFMA(fa[i], fb[j], acc[i][j]);
        }
    }
#pragma unroll
    for (int i = 0; i < 4; ++i)
#pragma unroll
        for (int j = 0; j < 4; ++j)
#pragma unroll
            for (int r = 0; r < 4; ++r) {
                int row = m0 + mo + i * 16 + (lane >> 4) * 4 + r;
                int col = n0 + no + j * 16 + (lane & 15);
                sbuf[(long)row * SEQ + col] = f2h(acc[i][j][r] * 0.03125f);
            }
}

// ============ softmax_pv: candidate softmax + fused sparse PV, writes O directly ============
// 1 wave per row. Candidates = entries with s~ > max-60 (p elsewhere < 5e-12, dropped).
// Exact fp32 logits from (yhi+ylo)·x; O[row] = sum_c p_c * x[c] (fp32 gather).
__global__ __launch_bounds__(128) void softmax_pv(const unsigned short* __restrict__ sh,
                                                  const unsigned short* __restrict__ yhi,
                                                  const unsigned short* __restrict__ ylo,
                                                  const float* __restrict__ x,
                                                  float* __restrict__ out, int b) {
    __shared__ int cnt[2];
    __shared__ int list[2][128];
    __shared__ float pval[2][128];
    int w = threadIdx.x >> 6, lane = threadIdx.x & 63;
    int row = blockIdx.x * 2 + w;
    const unsigned short* srow = sh + (long)row * SEQ;
    if (lane == 0) cnt[w] = 0;

    // phase 1: row -> regs (64 fp16/lane), max
    v8s sv[8];
#pragma unroll
    for (int j = 0; j < 8; ++j) sv[j] = *(const v8s*)(srow + j * 512 + lane * 8);
    float mhat = -INFINITY;
#pragma unroll
    for (int j = 0; j < 8; ++j)
#pragma unroll
        for (int e = 0; e < 8; ++e) mhat = fmaxf(mhat, h2f((unsigned short)sv[j][e]));
#pragma unroll
    for (int o = 1; o < 64; o <<= 1) mhat = fmaxf(mhat, __shfl_xor(mhat, o));

    // phase 2: candidate detection (window 60)
    float T = mhat - 60.0f;
#pragma unroll
    for (int j = 0; j < 8; ++j)
#pragma unroll
        for (int e = 0; e < 8; ++e) {
            if (h2f((unsigned short)sv[j][e]) > T) {
                int idx = atomicAdd(&cnt[w], 1);
                if (idx < 128) list[w][idx] = j * 512 + lane * 8 + e;
            }
        }
    __syncthreads();
    int n = cnt[w] < 128 ? cnt[w] : 128;

    // phase 3: exact logits for candidates (wave-cooperative fp32 dot)
    long ybase = ((long)b * SEQ + row) * ED;
    int k0 = lane * 16;
    v8s yh0 = *(const v8s*)(yhi + ybase + k0);
    v8s yh1 = *(const v8s*)(yhi + ybase + k0 + 8);
    v8s yl0 = *(const v8s*)(ylo + ybase + k0);
    v8s yl1 = *(const v8s*)(ylo + ybase + k0 + 8);
    float yv[16];
#pragma unroll
    for (int e = 0; e < 8; ++e) {
        yv[e]     = bf2f((unsigned short)yh0[e]) + bf2f((unsigned short)yl0[e]);
        yv[8 + e] = bf2f((unsigned short)yh1[e]) + bf2f((unsigned short)yl1[e]);
    }
    float M = -INFINITY;
    for (int c = 0; c < n; ++c) {
        const float* xr = x + ((long)b * SEQ + list[w][c]) * ED + k0;
        float s = 0.f;
#pragma unroll
        for (int t = 0; t < 4; ++t) {
            v4f xv = *(const v4f*)(xr + t * 4);
#pragma unroll
            for (int e = 0; e < 4; ++e) s += yv[t * 4 + e] * xv[e];
        }
#pragma unroll
        for (int o = 1; o < 64; o <<= 1) s += __shfl_xor(s, o);
        s *= 0.03125f;
        if (lane == 0) pval[w][c] = s;
        M = fmaxf(M, s);
    }

    // phase 4: weights + sparse PV
    float sum = 0.f;
    for (int c = 0; c < n; ++c) sum += __expf(pval[w][c] - M);
    float inv = 1.0f / sum;
    v4f a0 = {0.f, 0.f, 0.f, 0.f}, a1 = a0, a2 = a0, a3 = a0;
    for (int c = 0; c < n; ++c) {
        float p = __expf(pval[w][c] - M) * inv;
        const float* xr = x + ((long)b * SEQ + list[w][c]) * ED + k0;
        v4f x0 = *(const v4f*)(xr);
        v4f x1 = *(const v4f*)(xr + 4);
        v4f x2 = *(const v4f*)(xr + 8);
        v4f x3 = *(const v4f*)(xr + 12);
#pragma unroll
        for (int e = 0; e < 4; ++e) {
            a0[e] += p * x0[e];
            a1[e] += p * x1[e];
            a2[e] += p * x2[e];
            a3[e] += p * x3[e];
        }
    }
    float* orow = out + ((long)b * SEQ + row) * ED + k0;
    *(v4f*)(orow)      = a0;
    *(v4f*)(orow + 4)  = a1;
    *(v4f*)(orow + 8)  = a2;
    *(v4f*)(orow + 12) = a3;
}

extern "C" void kernel_launch(void* const* d_in, const int* in_sizes, int n_in,
                              void* d_out, int out_size, void* d_ws, size_t ws_size,
                              hipStream_t stream) {
    const float* x  = (const float*)d_in[0];
    const float* wq = (const float*)d_in[1];
    const float* wk = (const float*)d_in[2];
    unsigned char* ws = (unsigned char*)d_ws;
    unsigned short* xhi = (unsigned short*)(ws + XHI_OFF);
    unsigned short* xlo = (unsigned short*)(ws + XLO_OFF);
    unsigned short* yhi = (unsigned short*)(ws + YHI_OFF);
    unsigned short* ylo = (unsigned short*)(ws + YLO_OFF);
    unsigned short* sbuf= (unsigned short*)(ws + SBUF_OFF);
    unsigned short* wqh = (unsigned short*)(ws + WQH_OFF);
    unsigned short* wql = (unsigned short*)(ws + WQL_OFF);
    unsigned short* wkh = (unsigned short*)(ws + WKH_OFF);
    unsigned short* wkl = (unsigned short*)(ws + WKL_OFF);
    unsigned short* mth = (unsigned short*)(ws + MTH_OFF);
    unsigned short* mtl = (unsigned short*)(ws + MTL_OFF);

    prep_x<<<16384, 256, 0, stream>>>(x, xhi, xlo);
    prep_w2<<<dim3(1024, 1, 2), 256, 0, stream>>>(wq, wk, wqh, wql, wkh, wkl);
    gemm_m<<<dim3(8, 8), 256, 0, stream>>>(wkh, wkl, wqh, wql, mth, mtl);
    gemm_y<<<dim3(128, 8), 256, 0, stream>>>(xhi, xlo, mth, mtl, yhi, ylo);
    for (int b = 0; b < NB; ++b) {
        gemm_s1<<<dim3(32, 32), 256, 0, stream>>>(yhi, xhi, sbuf, b);
        softmax_pv<<<2048, 128, 0, stream>>>(sbuf, yhi, ylo, x, (float*)d_out, b);
    }
}